// Round 4
// baseline (1065.405 us; speedup 1.0000x reference)
//
#include <hip/hip_runtime.h>

constexpr int FEAT = 128;

typedef __attribute__((ext_vector_type(8))) short bf16x8;
typedef __attribute__((ext_vector_type(4))) float f32x4;

// ---------- bf16 helpers (round-to-nearest-even) ----------
__device__ inline unsigned short bf16r(float a) {
  unsigned int ua = __builtin_bit_cast(unsigned int, a);
  ua = ua + 0x7fffu + ((ua >> 16) & 1u);
  return (unsigned short)(ua >> 16);
}
// split v into hi (bf16 RNE) and lo (bf16 of exact residual)
__device__ inline void split2(float v, unsigned short& hs, unsigned short& ls2) {
  unsigned int u = __builtin_bit_cast(unsigned int, v);
  unsigned int rh = (u + 0x7fffu + ((u >> 16) & 1u)) & 0xffff0000u;
  hs = (unsigned short)(rh >> 16);
  float hf = __builtin_bit_cast(float, rh);
  ls2 = bf16r(v - hf);
}

// ---------- fp16 helpers (gather-buffer dtype; NOT an MFMA operand) ----------
__device__ inline unsigned int halfpair(float a, float b) {
  unsigned short ua = __builtin_bit_cast(unsigned short, (_Float16)a);
  unsigned short ub = __builtin_bit_cast(unsigned short, (_Float16)b);
  return (unsigned int)ua | ((unsigned int)ub << 16);
}
__device__ inline float2 halfup(unsigned int u) {
  _Float16 lo = __builtin_bit_cast(_Float16, (unsigned short)(u & 0xffffu));
  _Float16 hi = __builtin_bit_cast(_Float16, (unsigned short)(u >> 16));
  return make_float2((float)lo, (float)hi);
}

// K-permutation for mfma_f32_16x16x32_bf16 B-operand fragments:
// lane (llo,lhi) in k-block s reads 8 contiguous bf16 at slot s*4+lhi.
__device__ __host__ inline int kperm(int k) {
  return ((k >> 5) << 5) + (((k >> 2) & 3) << 3) + (((k >> 4) & 1) << 2) + (k & 3);
}

// ---------------- CSR build ----------------

__global__ void count_kernel(const int* __restrict__ dst, int* __restrict__ deg, int E) {
  int e = blockIdx.x * blockDim.x + threadIdx.x;
  if (e < E) atomicAdd(&deg[dst[e]], 1);
}

__global__ __launch_bounds__(1024) void scan_kernel(const int* __restrict__ in,
                                                    int* __restrict__ out, int n) {
  __shared__ int wsum[16];
  __shared__ int carry;
  int tid = threadIdx.x;
  if (tid == 0) carry = 0;
  __syncthreads();
  int lane = tid & 63, wid = tid >> 6;
  for (int base = 0; base < n; base += 1024) {
    int i = base + tid;
    int v = (i < n) ? in[i] : 0;
    int s = v;
#pragma unroll
    for (int off = 1; off < 64; off <<= 1) {
      int t = __shfl_up(s, off);
      if (lane >= off) s += t;
    }
    if (lane == 63) wsum[wid] = s;
    __syncthreads();
    if (tid < 16) {
      int ws2 = wsum[tid];
#pragma unroll
      for (int off = 1; off < 16; off <<= 1) {
        int t = __shfl_up(ws2, off, 16);
        if ((tid & 15) >= off) ws2 += t;
      }
      wsum[tid] = ws2;
    }
    __syncthreads();
    int excl = carry + (wid ? wsum[wid - 1] : 0) + (s - v);
    if (i < n) out[i] = excl;
    __syncthreads();
    if (tid == 0) carry += wsum[15];
    __syncthreads();
  }
}

__global__ void fill_kernel(const int* __restrict__ src, const int* __restrict__ dst,
                            int* __restrict__ cursor, int* __restrict__ col, int E) {
  int e = blockIdx.x * blockDim.x + threadIdx.x;
  if (e < E) {
    int p = atomicAdd(&cursor[dst[e]], 1);
    col[p] = src[e];
  }
}

// ---------------- x fp32 -> fp16 (gather copy) ----------------

__global__ void convert_kernel(const float* __restrict__ x, unsigned short* __restrict__ xb,
                               int n4) {
  int idx = blockIdx.x * blockDim.x + threadIdx.x;
  if (idx >= n4) return;
  float4 v = ((const float4*)x)[idx];
  uint2 o;
  o.x = halfpair(v.x, v.y);
  o.y = halfpair(v.z, v.w);
  ((uint2*)xb)[idx] = o;
}

// ---------------- weight fp32 [k][n] -> hi/lo bf16 LDS-images [n][swz(perm(k))] ----------------

__global__ void wconv_kernel(const float* __restrict__ w, unsigned short* __restrict__ dhi,
                             unsigned short* __restrict__ dlo) {
  int idx = blockIdx.x * blockDim.x + threadIdx.x;
  if (idx >= FEAT * FEAT) return;
  int k = idx >> 7, n = idx & 127;
  unsigned short hs, ls2;
  split2(w[idx], hs, ls2);
  int p = kperm(k);
  int slot = p >> 3, e = p & 7;
  int off = n * FEAT + ((slot ^ (n & 7)) << 3) + e;
  dhi[off] = hs;
  dlo[off] = ls2;
}

// ---------------- aggregation: 2 nodes per wave (32 lanes, uint2=4 fp16 each), f32 out ----------

__global__ void agg_kernel(const unsigned short* __restrict__ x, const int* __restrict__ rowptr,
                           const int* __restrict__ col, float* __restrict__ agg, int N) {
  int gid = blockIdx.x * blockDim.x + threadIdx.x;
  int wid = gid >> 6;
  int lane = threadIdx.x & 63;
  int node = wid * 2 + (lane >> 5);
  if (node >= N) return;
  int ln = lane & 31;
  const uint2* xr = (const uint2*)x;  // 32 uint2 per row
  uint2 s = xr[(size_t)node * 32 + ln];
  float2 p01 = halfup(s.x), p23 = halfup(s.y);
  float a0 = p01.x, a1 = p01.y, a2 = p23.x, a3 = p23.y;
  int e0 = rowptr[node], e1 = rowptr[node + 1];
  for (int e = e0; e < e1; e++) {
    int c = col[e];
    uint2 v = xr[(size_t)c * 32 + ln];
    float2 v01 = halfup(v.x), v23 = halfup(v.y);
    a0 += v01.x; a1 += v01.y; a2 += v23.x; a3 += v23.y;
  }
  *(float4*)&agg[(size_t)node * FEAT + ln * 4] = make_float4(a0, a1, a2, a3);
}

// ---------------- split-precision MFMA GEMM ----------------
// C = relu(A[Nx128] @ W[128x128] + b); A f32 in memory, split hi/lo during LDS staging;
// W pre-split hi/lo images. 3 MFMA passes: Ah*Wh + Ah*Wl + Al*Wh (f32-accurate).
// 128x128 tile, 4 waves (2x2), swapped operands -> lane owns 4 consecutive out cols.

__global__ __launch_bounds__(256) void gemm_kernel(
    const float* __restrict__ A, const unsigned short* __restrict__ Whi,
    const unsigned short* __restrict__ Wlo, const float* __restrict__ bias,
    float* __restrict__ C, unsigned short* __restrict__ Cb,
    float* __restrict__ colsum, float* __restrict__ colsumsq,
    int N, int doStats, int wF32) {
  __shared__ unsigned short Ah[FEAT * FEAT];   // 32KB each
  __shared__ unsigned short Al[FEAT * FEAT];
  __shared__ unsigned short Wh[FEAT * FEAT];
  __shared__ unsigned short Wl[FEAT * FEAT];

  int tx = threadIdx.x;
  int row0 = blockIdx.x * FEAT;

#pragma unroll
  for (int i = 0; i < 8; i++) {
    int idx = tx + i * 256;
    ((uint4*)Wh)[idx] = ((const uint4*)Whi)[idx];
    ((uint4*)Wl)[idx] = ((const uint4*)Wlo)[idx];
  }
#pragma unroll
  for (int i = 0; i < 16; i++) {
    int idx = tx + i * 256;  // 4096 float4 chunks = 128 rows x 32
    int r = idx >> 5;
    int c = idx & 31;
    float4 v = make_float4(0.f, 0.f, 0.f, 0.f);
    if (row0 + r < N) v = ((const float4*)(A + (size_t)(row0 + r) * FEAT))[c];
    int k0 = c << 2;
    int p0 = ((k0 >> 5) << 5) + (((k0 >> 2) & 3) << 3) + (((k0 >> 4) & 1) << 2);
    int slot = p0 >> 3, half4 = (p0 >> 2) & 1;
    int off = r * FEAT + ((slot ^ (r & 7)) << 3) + (half4 << 2);
    unsigned short h0, h1, h2, h3, l0, l1, l2, l3;
    split2(v.x, h0, l0);
    split2(v.y, h1, l1);
    split2(v.z, h2, l2);
    split2(v.w, h3, l3);
    *(uint2*)&Ah[off] =
        make_uint2((unsigned)h0 | ((unsigned)h1 << 16), (unsigned)h2 | ((unsigned)h3 << 16));
    *(uint2*)&Al[off] =
        make_uint2((unsigned)l0 | ((unsigned)l1 << 16), (unsigned)l2 | ((unsigned)l3 << 16));
  }
  __syncthreads();

  int w = tx >> 6;
  int l = tx & 63;
  int llo = l & 15, lhi = l >> 4;
  int wr = (w >> 1) * 64, wc = (w & 1) * 64;

  f32x4 acc[4][4];
#pragma unroll
  for (int mi = 0; mi < 4; mi++)
#pragma unroll
    for (int nj = 0; nj < 4; nj++) acc[mi][nj] = (f32x4)(0.f);

#pragma unroll
  for (int s = 0; s < 4; s++) {
    bf16x8 ah[4], al[4], wh[4], wl2[4];
#pragma unroll
    for (int mi = 0; mi < 4; mi++) {
      int row = wr + mi * 16 + llo;
      int base = row * FEAT + ((((s << 2) + lhi) ^ (row & 7)) << 3);
      ah[mi] = *(const bf16x8*)&Ah[base];
      al[mi] = *(const bf16x8*)&Al[base];
    }
#pragma unroll
    for (int nj = 0; nj < 4; nj++) {
      int n = wc + nj * 16 + llo;
      int base = n * FEAT + ((((s << 2) + lhi) ^ (n & 7)) << 3);
      wh[nj] = *(const bf16x8*)&Wh[base];
      wl2[nj] = *(const bf16x8*)&Wl[base];
    }
#pragma unroll
    for (int mi = 0; mi < 4; mi++)
#pragma unroll
      for (int nj = 0; nj < 4; nj++) {
        acc[mi][nj] = __builtin_amdgcn_mfma_f32_16x16x32_bf16(wh[nj], ah[mi], acc[mi][nj], 0, 0, 0);
        acc[mi][nj] = __builtin_amdgcn_mfma_f32_16x16x32_bf16(wl2[nj], ah[mi], acc[mi][nj], 0, 0, 0);
        acc[mi][nj] = __builtin_amdgcn_mfma_f32_16x16x32_bf16(wh[nj], al[mi], acc[mi][nj], 0, 0, 0);
      }
  }

  // epilogue: bias, relu, optional f32/fp16 stores, optional col stats
#pragma unroll
  for (int nj = 0; nj < 4; nj++) {
    int colb = wc + nj * 16 + lhi * 4;
    float4 bb = *(const float4*)&bias[colb];
    float ps[4] = {0.f, 0.f, 0.f, 0.f}, pq[4] = {0.f, 0.f, 0.f, 0.f};
#pragma unroll
    for (int mi = 0; mi < 4; mi++) {
      int row = row0 + wr + mi * 16 + llo;
      f32x4 v = acc[mi][nj];
      float v0 = fmaxf(v[0] + bb.x, 0.f);
      float v1 = fmaxf(v[1] + bb.y, 0.f);
      float v2 = fmaxf(v[2] + bb.z, 0.f);
      float v3 = fmaxf(v[3] + bb.w, 0.f);
      if (row < N) {
        if (wF32) *(float4*)&C[(size_t)row * FEAT + colb] = make_float4(v0, v1, v2, v3);
        if (Cb) *(uint2*)&Cb[(size_t)row * FEAT + colb] =
            make_uint2(halfpair(v0, v1), halfpair(v2, v3));
        ps[0] += v0; ps[1] += v1; ps[2] += v2; ps[3] += v3;
        pq[0] += v0 * v0; pq[1] += v1 * v1; pq[2] += v2 * v2; pq[3] += v3 * v3;
      }
    }
    if (doStats) {
#pragma unroll
      for (int r = 0; r < 4; r++) {
        float s2 = ps[r], q2 = pq[r];
#pragma unroll
        for (int off = 1; off < 16; off <<= 1) {
          s2 += __shfl_xor(s2, off);
          q2 += __shfl_xor(q2, off);
        }
        if (llo == 0) {
          atomicAdd(&colsum[colb + r], s2);
          atomicAdd(&colsumsq[colb + r], q2);
        }
      }
    }
  }
}

// ---------------- fold BN into gemm2 weights (hi/lo LDS-image out) ----------------

__global__ __launch_bounds__(128) void fold_kernel(
    const float* __restrict__ colsum, const float* __restrict__ colsumsq,
    const float* __restrict__ gamma, const float* __restrict__ beta,
    const float* __restrict__ w2, const float* __restrict__ b2,
    unsigned short* __restrict__ w2fhi, unsigned short* __restrict__ w2flo,
    float* __restrict__ b2f, int N) {
  __shared__ float sc[FEAT], sh[FEAT];
  int c = threadIdx.x;
  float invN = 1.0f / (float)N;
  float mean = colsum[c] * invN;
  float var = colsumsq[c] * invN - mean * mean;
  float rstd = rsqrtf(var + 1e-5f);
  float scale = gamma[c] * rstd;
  float shift = beta[c] - mean * scale;
  sc[c] = scale;
  sh[c] = shift;
  __syncthreads();
  float bacc = b2[c];
  for (int k = 0; k < FEAT; k++) {
    float wv = w2[k * FEAT + c];
    bacc += sh[k] * wv;
    unsigned short hs, ls2;
    split2(sc[k] * wv, hs, ls2);
    int p = kperm(k);
    int slot = p >> 3, e = p & 7;
    w2fhi[c * FEAT + ((slot ^ (c & 7)) << 3) + e] = hs;
    w2flo[c * FEAT + ((slot ^ (c & 7)) << 3) + e] = ls2;
  }
  b2f[c] = bacc;
}

// ---------------- final fc2 (f32 in) ----------------

__global__ void fc2_kernel(const float* __restrict__ h, const float* __restrict__ w,
                           const float* __restrict__ b, float* __restrict__ out, int N) {
  int gid = blockIdx.x * blockDim.x + threadIdx.x;
  int node = gid >> 6;
  if (node >= N) return;
  int lane = threadIdx.x & 63;
  float2 hv = ((const float2*)(h + (size_t)node * FEAT))[lane];
  float2 wv = ((const float2*)w)[lane];
  float s = hv.x * wv.x + hv.y * wv.y;
#pragma unroll
  for (int off = 32; off; off >>= 1) s += __shfl_xor(s, off);
  if (lane == 0) out[node] = s + b[0];
}

// ---------------- launch ----------------

extern "C" void kernel_launch(void* const* d_in, const int* in_sizes, int n_in,
                              void* d_out, int out_size, void* d_ws, size_t ws_size,
                              hipStream_t stream) {
  const float* x     = (const float*)d_in[0];
  const int*   ei    = (const int*)d_in[1];
  const float* w1    = (const float*)d_in[2];
  const float* b1    = (const float*)d_in[3];
  const float* gamma = (const float*)d_in[4];
  const float* beta  = (const float*)d_in[5];
  const float* w2    = (const float*)d_in[6];
  const float* b2    = (const float*)d_in[7];
  const float* fc1w  = (const float*)d_in[8];
  const float* fc1b  = (const float*)d_in[9];
  const float* fc2w  = (const float*)d_in[10];
  const float* fc2b  = (const float*)d_in[11];
  float* out = (float*)d_out;

  int N = in_sizes[0] / FEAT;  // 50000
  int E = in_sizes[1] / 2;     // 600000
  const int* srcI = ei;
  const int* dstI = ei + E;

  size_t Nf = (size_t)N * FEAT;
  unsigned short* hb = (unsigned short*)d_ws;          // fp16 gather copy (x, then h1..h3)
  float* F0 = (float*)(hb + Nf);                       // f32 activation chain (in-place GEMMs)
  unsigned short* whi = (unsigned short*)(F0 + Nf);    // 5 pre-split weight images
  unsigned short* wlo = whi + 5 * FEAT * FEAT;
  unsigned short* w2fhi = wlo + 5 * FEAT * FEAT;
  unsigned short* w2flo = w2fhi + FEAT * FEAT;
  float* b2f = (float*)(w2flo + FEAT * FEAT);
  float* colsum = b2f + FEAT;
  float* colsumsq = colsum + FEAT;
  int* deg = (int*)(colsumsq + FEAT);
  int* rowptr = deg + (N + 1);
  int* cursor = rowptr + (N + 1);
  int* col = cursor + (N + 1);

  // CSR build
  hipMemsetAsync(deg, 0, (N + 1) * sizeof(int), stream);
  count_kernel<<<(E + 255) / 256, 256, 0, stream>>>(dstI, deg, E);
  scan_kernel<<<1, 1024, 0, stream>>>(deg, rowptr, N + 1);
  hipMemcpyAsync(cursor, rowptr, (N + 1) * sizeof(int), hipMemcpyDeviceToDevice, stream);
  fill_kernel<<<(E + 255) / 256, 256, 0, stream>>>(srcI, dstI, cursor, col, E);

  // fp16 copy of x for gather; pre-split weights
  int n4 = (int)(Nf / 4);
  convert_kernel<<<(n4 + 255) / 256, 256, 0, stream>>>(x, hb, n4);
  for (int l = 0; l < 4; l++)
    wconv_kernel<<<64, 256, 0, stream>>>(w1 + (size_t)l * FEAT * FEAT,
                                         whi + (size_t)l * FEAT * FEAT,
                                         wlo + (size_t)l * FEAT * FEAT);
  wconv_kernel<<<64, 256, 0, stream>>>(fc1w, whi + (size_t)4 * FEAT * FEAT,
                                       wlo + (size_t)4 * FEAT * FEAT);

  int aggBlocks = ((N + 1) / 2 * 64 + 255) / 256;
  int fc2Blocks = (int)(((size_t)N * 64 + 255) / 256);
  int gemmBlocks = (N + FEAT - 1) / FEAT;

  for (int l = 0; l < 4; l++) {
    // agg: gather fp16 h (or x), write f32 into F0
    agg_kernel<<<aggBlocks, 256, 0, stream>>>(hb, rowptr, col, F0, N);
    hipMemsetAsync(colsum, 0, 2 * FEAT * sizeof(float), stream);
    // gemm1 in-place F0 -> F0 (f32), with BN stats
    gemm_kernel<<<gemmBlocks, 256, 0, stream>>>(
        F0, whi + (size_t)l * FEAT * FEAT, wlo + (size_t)l * FEAT * FEAT,
        b1 + (size_t)l * FEAT, F0, nullptr, colsum, colsumsq, N, 1, 1);
    fold_kernel<<<1, FEAT, 0, stream>>>(colsum, colsumsq, gamma + (size_t)l * FEAT,
                                        beta + (size_t)l * FEAT,
                                        w2 + (size_t)l * FEAT * FEAT,
                                        b2 + (size_t)l * FEAT, w2fhi, w2flo, b2f, N);
    // gemm2: layers 0-2 -> fp16 gather buffer only; layer 3 -> f32 (feeds fc1)
    if (l < 3) {
      gemm_kernel<<<gemmBlocks, 256, 0, stream>>>(F0, w2fhi, w2flo, b2f, F0, hb,
                                                  colsum, colsumsq, N, 0, 0);
    } else {
      gemm_kernel<<<gemmBlocks, 256, 0, stream>>>(F0, w2fhi, w2flo, b2f, F0, nullptr,
                                                  colsum, colsumsq, N, 0, 1);
    }
  }

  // fc1 in-place F0 -> F0 (relu), then fc2 dot
  gemm_kernel<<<gemmBlocks, 256, 0, stream>>>(F0, whi + (size_t)4 * FEAT * FEAT,
                                              wlo + (size_t)4 * FEAT * FEAT, fc1b, F0,
                                              nullptr, colsum, colsumsq, N, 0, 1);
  fc2_kernel<<<fc2Blocks, 256, 0, stream>>>(F0, fc2w, fc2b, out, N);
}

// Round 5
// 954.542 us; speedup vs baseline: 1.1161x; 1.1161x over previous
//
#include <hip/hip_runtime.h>

constexpr int FEAT = 128;

typedef __attribute__((ext_vector_type(8))) _Float16 f16x8;
typedef __attribute__((ext_vector_type(4))) float f32x4;

// ---------- fp16 helpers ----------
__device__ inline unsigned int halfpair(float a, float b) {
  unsigned short ua = __builtin_bit_cast(unsigned short, (_Float16)a);
  unsigned short ub = __builtin_bit_cast(unsigned short, (_Float16)b);
  return (unsigned int)ua | ((unsigned int)ub << 16);
}
__device__ inline unsigned short halfr(float a) {
  return __builtin_bit_cast(unsigned short, (_Float16)a);
}
__device__ inline float2 halfup(unsigned int u) {
  _Float16 lo = __builtin_bit_cast(_Float16, (unsigned short)(u & 0xffffu));
  _Float16 hi = __builtin_bit_cast(_Float16, (unsigned short)(u >> 16));
  return make_float2((float)lo, (float)hi);
}

// K-permutation for mfma 16x16x32 fragments: lane (llo,lhi) in k-block s reads
// 8 contiguous elems at slot s*4+lhi. (layout verified by round-1/round-4 passes)
__device__ __host__ inline int kperm(int k) {
  return ((k >> 5) << 5) + (((k >> 2) & 3) << 3) + (((k >> 4) & 1) << 2) + (k & 3);
}

// ---------------- CSR build ----------------

__global__ void count_kernel(const int* __restrict__ dst, int* __restrict__ deg, int E) {
  int e = blockIdx.x * blockDim.x + threadIdx.x;
  if (e < E) atomicAdd(&deg[dst[e]], 1);
}

__global__ __launch_bounds__(1024) void scan_kernel(const int* __restrict__ in,
                                                    int* __restrict__ out,
                                                    int* __restrict__ out2, int n) {
  __shared__ int wsum[16];
  __shared__ int carry;
  int tid = threadIdx.x;
  if (tid == 0) carry = 0;
  __syncthreads();
  int lane = tid & 63, wid = tid >> 6;
  for (int base = 0; base < n; base += 1024) {
    int i = base + tid;
    int v = (i < n) ? in[i] : 0;
    int s = v;
#pragma unroll
    for (int off = 1; off < 64; off <<= 1) {
      int t = __shfl_up(s, off);
      if (lane >= off) s += t;
    }
    if (lane == 63) wsum[wid] = s;
    __syncthreads();
    if (tid < 16) {
      int ws2 = wsum[tid];
#pragma unroll
      for (int off = 1; off < 16; off <<= 1) {
        int t = __shfl_up(ws2, off, 16);
        if ((tid & 15) >= off) ws2 += t;
      }
      wsum[tid] = ws2;
    }
    __syncthreads();
    int excl = carry + (wid ? wsum[wid - 1] : 0) + (s - v);
    if (i < n) { out[i] = excl; out2[i] = excl; }
    __syncthreads();
    if (tid == 0) carry += wsum[15];
    __syncthreads();
  }
}

__global__ void fill_kernel(const int* __restrict__ src, const int* __restrict__ dst,
                            int* __restrict__ cursor, int* __restrict__ col, int E) {
  int e = blockIdx.x * blockDim.x + threadIdx.x;
  if (e < E) {
    int p = atomicAdd(&cursor[dst[e]], 1);
    col[p] = src[e];
  }
}

// ---------------- x fp32 -> fp16 ----------------

__global__ void convert_kernel(const float* __restrict__ x, unsigned short* __restrict__ xb,
                               int n4) {
  int idx = blockIdx.x * blockDim.x + threadIdx.x;
  if (idx >= n4) return;
  float4 v = ((const float4*)x)[idx];
  uint2 o;
  o.x = halfpair(v.x, v.y);
  o.y = halfpair(v.z, v.w);
  ((uint2*)xb)[idx] = o;
}

// ---------------- weights fp32 [k][n] -> fp16 LDS-image [n][swz(perm(k))] ----------------
// 5 matrices: w1[0..3] (contiguous), then fc1w.

__global__ void wconv_kernel(const float* __restrict__ w1, const float* __restrict__ fc1w,
                             unsigned short* __restrict__ dst) {
  int idx = blockIdx.x * blockDim.x + threadIdx.x;  // 5*16384
  if (idx >= 5 * FEAT * FEAT) return;
  int m = idx >> 14;
  int r = idx & (FEAT * FEAT - 1);
  int k = r >> 7, n = r & 127;
  float v = (m < 4) ? w1[idx] : fc1w[r];
  int p = kperm(k);
  int slot = p >> 3, e = p & 7;
  dst[m * FEAT * FEAT + n * FEAT + ((slot ^ (n & 7)) << 3) + e] = halfr(v);
}

// ---------------- aggregation: 2 nodes/wave, 4 fp16 per lane, unroll-2 edges ----------------

__global__ void agg_kernel(const unsigned short* __restrict__ x, const int* __restrict__ rowptr,
                           const int* __restrict__ col, unsigned short* __restrict__ agg, int N) {
  int gid = blockIdx.x * blockDim.x + threadIdx.x;
  int wid = gid >> 6;
  int lane = threadIdx.x & 63;
  int node = wid * 2 + (lane >> 5);
  if (node >= N) return;
  int ln = lane & 31;
  const uint2* xr = (const uint2*)x;  // 32 uint2 per row
  uint2 s = xr[(size_t)node * 32 + ln];
  float2 p01 = halfup(s.x), p23 = halfup(s.y);
  float a0 = p01.x, a1 = p01.y, a2 = p23.x, a3 = p23.y;
  float b0 = 0.f, b1 = 0.f, b2 = 0.f, b3 = 0.f;
  int e0 = rowptr[node], e1 = rowptr[node + 1];
  int e = e0;
  for (; e + 1 < e1; e += 2) {
    int c0 = col[e], c1 = col[e + 1];
    uint2 v = xr[(size_t)c0 * 32 + ln];
    uint2 u = xr[(size_t)c1 * 32 + ln];
    float2 v01 = halfup(v.x), v23 = halfup(v.y);
    float2 u01 = halfup(u.x), u23 = halfup(u.y);
    a0 += v01.x; a1 += v01.y; a2 += v23.x; a3 += v23.y;
    b0 += u01.x; b1 += u01.y; b2 += u23.x; b3 += u23.y;
  }
  if (e < e1) {
    uint2 v = xr[(size_t)col[e] * 32 + ln];
    float2 v01 = halfup(v.x), v23 = halfup(v.y);
    a0 += v01.x; a1 += v01.y; a2 += v23.x; a3 += v23.y;
  }
  a0 += b0; a1 += b1; a2 += b2; a3 += b3;
  uint2 o;
  o.x = halfpair(a0, a1);
  o.y = halfpair(a2, a3);
  ((uint2*)agg)[(size_t)node * 32 + ln] = o;
}

// ---------------- fp16 MFMA GEMM: C = relu(A@W + b), fp32 acc ----------------
// 128x128 tile, 4 waves (2x2), swapped operands mfma(W,A) -> lane owns 4 consecutive
// out cols. LDS 64KB -> 2 blocks/CU. Stats -> per-block partials (no global atomics).

__global__ __launch_bounds__(256) void gemm_kernel(
    const unsigned short* __restrict__ A, const unsigned short* __restrict__ Wimg,
    const float* __restrict__ bias, unsigned short* __restrict__ C,
    float* __restrict__ pS, float* __restrict__ pQ, int N, int doStats) {
  __shared__ unsigned short Al[FEAT * FEAT];  // 32KB
  __shared__ unsigned short Wl[FEAT * FEAT];  // 32KB
  __shared__ float ls[FEAT], lq[FEAT];

  int tx = threadIdx.x;
  int row0 = blockIdx.x * FEAT;
  if (tx < FEAT) { ls[tx] = 0.f; lq[tx] = 0.f; }

  // stage W: straight copy (pre-layouted in global)
#pragma unroll
  for (int i = 0; i < 8; i++) {
    int idx = tx + i * 256;
    ((uint4*)Wl)[idx] = ((const uint4*)Wimg)[idx];
  }
  // stage A: perm+swizzle, uint2 = 4 fp16 (4-aligned k chunk stays contiguous)
#pragma unroll
  for (int i = 0; i < 16; i++) {
    int idx = tx + i * 256;  // 4096 uint2 chunks = 128 rows x 32
    int r = idx >> 5;
    int c = idx & 31;
    uint2 v = make_uint2(0u, 0u);
    if (row0 + r < N) v = ((const uint2*)(A + (size_t)(row0 + r) * FEAT))[c];
    int k0 = c << 2;
    int p0 = ((k0 >> 5) << 5) + (((k0 >> 2) & 3) << 3) + (((k0 >> 4) & 1) << 2);
    int slot = p0 >> 3, half4 = (p0 >> 2) & 1;
    *(uint2*)&Al[r * FEAT + ((slot ^ (r & 7)) << 3) + (half4 << 2)] = v;
  }
  __syncthreads();

  int w = tx >> 6;
  int l = tx & 63;
  int llo = l & 15, lhi = l >> 4;
  int wr = (w >> 1) * 64, wc = (w & 1) * 64;

  f32x4 acc[4][4];
#pragma unroll
  for (int mi = 0; mi < 4; mi++)
#pragma unroll
    for (int nj = 0; nj < 4; nj++) acc[mi][nj] = (f32x4)(0.f);

#pragma unroll
  for (int s = 0; s < 4; s++) {
    f16x8 af[4], wf[4];
#pragma unroll
    for (int mi = 0; mi < 4; mi++) {
      int row = wr + mi * 16 + llo;
      int base = row * FEAT + ((((s << 2) + lhi) ^ (row & 7)) << 3);
      af[mi] = *(const f16x8*)&Al[base];
    }
#pragma unroll
    for (int nj = 0; nj < 4; nj++) {
      int n = wc + nj * 16 + llo;
      int base = n * FEAT + ((((s << 2) + lhi) ^ (n & 7)) << 3);
      wf[nj] = *(const f16x8*)&Wl[base];
    }
#pragma unroll
    for (int mi = 0; mi < 4; mi++)
#pragma unroll
      for (int nj = 0; nj < 4; nj++)
        acc[mi][nj] = __builtin_amdgcn_mfma_f32_16x16x32_f16(wf[nj], af[mi], acc[mi][nj], 0, 0, 0);
  }

  // epilogue: bias, relu, fp16 store, LDS-staged stats
#pragma unroll
  for (int nj = 0; nj < 4; nj++) {
    int colb = wc + nj * 16 + lhi * 4;
    float4 bb = *(const float4*)&bias[colb];
    float ps[4] = {0.f, 0.f, 0.f, 0.f}, pq[4] = {0.f, 0.f, 0.f, 0.f};
#pragma unroll
    for (int mi = 0; mi < 4; mi++) {
      int row = row0 + wr + mi * 16 + llo;
      f32x4 v = acc[mi][nj];
      float v0 = fmaxf(v[0] + bb.x, 0.f);
      float v1 = fmaxf(v[1] + bb.y, 0.f);
      float v2 = fmaxf(v[2] + bb.z, 0.f);
      float v3 = fmaxf(v[3] + bb.w, 0.f);
      if (row < N) {
        *(uint2*)&C[(size_t)row * FEAT + colb] = make_uint2(halfpair(v0, v1), halfpair(v2, v3));
        ps[0] += v0; ps[1] += v1; ps[2] += v2; ps[3] += v3;
        pq[0] += v0 * v0; pq[1] += v1 * v1; pq[2] += v2 * v2; pq[3] += v3 * v3;
      }
    }
    if (doStats) {
#pragma unroll
      for (int r = 0; r < 4; r++) {
        float s2 = ps[r], q2 = pq[r];
#pragma unroll
        for (int off = 1; off < 16; off <<= 1) {
          s2 += __shfl_xor(s2, off);
          q2 += __shfl_xor(q2, off);
        }
        if (llo == 0) {
          atomicAdd(&ls[colb + r], s2);   // LDS atomics only
          atomicAdd(&lq[colb + r], q2);
        }
      }
    }
  }
  if (doStats) {
    __syncthreads();
    if (tx < FEAT) {
      pS[(size_t)blockIdx.x * FEAT + tx] = ls[tx];
      pQ[(size_t)blockIdx.x * FEAT + tx] = lq[tx];
    }
  }
}

// ---------------- fold: reduce partials, BN -> gemm2 weight image (fp16) ----------------

__global__ __launch_bounds__(128) void fold_kernel(
    const float* __restrict__ pS, const float* __restrict__ pQ, int nblk,
    const float* __restrict__ gamma, const float* __restrict__ beta,
    const float* __restrict__ w2, const float* __restrict__ b2,
    unsigned short* __restrict__ w2f, float* __restrict__ b2f, int N) {
  __shared__ float sc[FEAT], sh[FEAT];
  int c = threadIdx.x;
  float s = 0.f, q = 0.f;
  for (int b = 0; b < nblk; b++) {
    s += pS[(size_t)b * FEAT + c];
    q += pQ[(size_t)b * FEAT + c];
  }
  float invN = 1.0f / (float)N;
  float mean = s * invN;
  float var = q * invN - mean * mean;
  float rstd = rsqrtf(var + 1e-5f);
  float scale = gamma[c] * rstd;
  float shift = beta[c] - mean * scale;
  sc[c] = scale;
  sh[c] = shift;
  __syncthreads();
  float bacc = b2[c];
  for (int k = 0; k < FEAT; k++) {
    float wv = w2[k * FEAT + c];
    bacc += sh[k] * wv;
    int p = kperm(k);
    int slot = p >> 3, e = p & 7;
    w2f[c * FEAT + ((slot ^ (c & 7)) << 3) + e] = halfr(sc[k] * wv);
  }
  b2f[c] = bacc;
}

// ---------------- final fc2 (fp16 in) ----------------

__global__ void fc2_kernel(const unsigned short* __restrict__ h, const float* __restrict__ w,
                           const float* __restrict__ b, float* __restrict__ out, int N) {
  int gid = blockIdx.x * blockDim.x + threadIdx.x;
  int node = gid >> 6;
  if (node >= N) return;
  int lane = threadIdx.x & 63;
  float2 hv = halfup(((const unsigned int*)h)[(size_t)node * 64 + lane]);
  float2 wv = ((const float2*)w)[lane];
  float s = hv.x * wv.x + hv.y * wv.y;
#pragma unroll
  for (int off = 32; off; off >>= 1) s += __shfl_xor(s, off);
  if (lane == 0) out[node] = s + b[0];
}

// ---------------- launch ----------------

extern "C" void kernel_launch(void* const* d_in, const int* in_sizes, int n_in,
                              void* d_out, int out_size, void* d_ws, size_t ws_size,
                              hipStream_t stream) {
  const float* x     = (const float*)d_in[0];
  const int*   ei    = (const int*)d_in[1];
  const float* w1    = (const float*)d_in[2];
  const float* b1    = (const float*)d_in[3];
  const float* gamma = (const float*)d_in[4];
  const float* beta  = (const float*)d_in[5];
  const float* w2    = (const float*)d_in[6];
  const float* b2    = (const float*)d_in[7];
  const float* fc1w  = (const float*)d_in[8];
  const float* fc1b  = (const float*)d_in[9];
  const float* fc2w  = (const float*)d_in[10];
  const float* fc2b  = (const float*)d_in[11];
  float* out = (float*)d_out;

  int N = in_sizes[0] / FEAT;  // 50000
  int E = in_sizes[1] / 2;     // 600000
  const int* srcI = ei;
  const int* dstI = ei + E;

  int gemmBlocks = (N + FEAT - 1) / FEAT;

  size_t Nf = (size_t)N * FEAT;
  unsigned short* H = (unsigned short*)d_ws;       // fp16 activations (gather source)
  unsigned short* G = H + Nf;                      // fp16 work buffer
  unsigned short* wimg = G + Nf;                   // 5 fp16 weight images (w1 x4, fc1)
  unsigned short* w2f = wimg + 5 * FEAT * FEAT;    // folded gemm2 weight image
  float* b2f = (float*)(w2f + FEAT * FEAT);
  float* pS = b2f + FEAT;
  float* pQ = pS + (size_t)gemmBlocks * FEAT;
  int* deg = (int*)(pQ + (size_t)gemmBlocks * FEAT);
  int* rowptr = deg + (N + 1);
  int* cursor = rowptr + (N + 1);
  int* col = cursor + (N + 1);

  // CSR build
  hipMemsetAsync(deg, 0, (N + 1) * sizeof(int), stream);
  count_kernel<<<(E + 255) / 256, 256, 0, stream>>>(dstI, deg, E);
  scan_kernel<<<1, 1024, 0, stream>>>(deg, rowptr, cursor, N + 1);
  fill_kernel<<<(E + 255) / 256, 256, 0, stream>>>(srcI, dstI, cursor, col, E);

  // fp16 conversions
  int n4 = (int)(Nf / 4);
  convert_kernel<<<(n4 + 255) / 256, 256, 0, stream>>>(x, H, n4);
  wconv_kernel<<<(5 * FEAT * FEAT + 255) / 256, 256, 0, stream>>>(w1, fc1w, wimg);

  int aggBlocks = (int)((((size_t)(N + 1) / 2) * 64 + 255) / 256);
  int fc2Blocks = (int)(((size_t)N * 64 + 255) / 256);

  for (int l = 0; l < 4; l++) {
    agg_kernel<<<aggBlocks, 256, 0, stream>>>(H, rowptr, col, G, N);
    gemm_kernel<<<gemmBlocks, 256, 0, stream>>>(G, wimg + (size_t)l * FEAT * FEAT,
                                                b1 + (size_t)l * FEAT, G, pS, pQ, N, 1);
    fold_kernel<<<1, FEAT, 0, stream>>>(pS, pQ, gemmBlocks, gamma + (size_t)l * FEAT,
                                        beta + (size_t)l * FEAT,
                                        w2 + (size_t)l * FEAT * FEAT,
                                        b2 + (size_t)l * FEAT, w2f, b2f, N);
    gemm_kernel<<<gemmBlocks, 256, 0, stream>>>(G, w2f, b2f, H, nullptr, nullptr, N, 0);
  }

  // fc1: H -> G (relu), fc2: G -> out
  gemm_kernel<<<gemmBlocks, 256, 0, stream>>>(H, wimg + (size_t)4 * FEAT * FEAT, fc1b, G,
                                              nullptr, nullptr, N, 0);
  fc2_kernel<<<fc2Blocks, 256, 0, stream>>>(G, fc2w, fc2b, out, N);
}

// Round 6
// 475.253 us; speedup vs baseline: 2.2418x; 2.0085x over previous
//
#include <hip/hip_runtime.h>

constexpr int FEAT = 128;

typedef __attribute__((ext_vector_type(8))) _Float16 f16x8;
typedef __attribute__((ext_vector_type(4))) float f32x4;

// ---------- fp16 helpers ----------
__device__ inline unsigned int halfpair(float a, float b) {
  unsigned short ua = __builtin_bit_cast(unsigned short, (_Float16)a);
  unsigned short ub = __builtin_bit_cast(unsigned short, (_Float16)b);
  return (unsigned int)ua | ((unsigned int)ub << 16);
}
__device__ inline unsigned short halfr(float a) {
  return __builtin_bit_cast(unsigned short, (_Float16)a);
}
__device__ inline float2 halfup(unsigned int u) {
  _Float16 lo = __builtin_bit_cast(_Float16, (unsigned short)(u & 0xffffu));
  _Float16 hi = __builtin_bit_cast(_Float16, (unsigned short)(u >> 16));
  return make_float2((float)lo, (float)hi);
}

// K-permutation for mfma 16x16x32 fragments (layout verified by passing rounds)
__device__ __host__ inline int kperm(int k) {
  return ((k >> 5) << 5) + (((k >> 2) & 3) << 3) + (((k >> 4) & 1) << 2) + (k & 3);
}

// ---------------- CSR build ----------------

__global__ void count_kernel(const int* __restrict__ dst, int* __restrict__ deg, int E) {
  int e = blockIdx.x * blockDim.x + threadIdx.x;
  if (e < E) atomicAdd(&deg[dst[e]], 1);
}

__global__ __launch_bounds__(1024) void scan_kernel(const int* __restrict__ in,
                                                    int* __restrict__ out,
                                                    int* __restrict__ out2, int n) {
  __shared__ int wsum[16];
  __shared__ int carry;
  int tid = threadIdx.x;
  if (tid == 0) carry = 0;
  __syncthreads();
  int lane = tid & 63, wid = tid >> 6;
  for (int base = 0; base < n; base += 1024) {
    int i = base + tid;
    int v = (i < n) ? in[i] : 0;
    int s = v;
#pragma unroll
    for (int off = 1; off < 64; off <<= 1) {
      int t = __shfl_up(s, off);
      if (lane >= off) s += t;
    }
    if (lane == 63) wsum[wid] = s;
    __syncthreads();
    if (tid < 16) {
      int ws2 = wsum[tid];
#pragma unroll
      for (int off = 1; off < 16; off <<= 1) {
        int t = __shfl_up(ws2, off, 16);
        if ((tid & 15) >= off) ws2 += t;
      }
      wsum[tid] = ws2;
    }
    __syncthreads();
    int excl = carry + (wid ? wsum[wid - 1] : 0) + (s - v);
    if (i < n) { out[i] = excl; out2[i] = excl; }
    __syncthreads();
    if (tid == 0) carry += wsum[15];
    __syncthreads();
  }
}

__global__ void fill_kernel(const int* __restrict__ src, const int* __restrict__ dst,
                            int* __restrict__ cursor, int* __restrict__ col, int E) {
  int e = blockIdx.x * blockDim.x + threadIdx.x;
  if (e < E) {
    int p = atomicAdd(&cursor[dst[e]], 1);
    col[p] = src[e];
  }
}

// ---------------- x fp32 -> fp16 ----------------

__global__ void convert_kernel(const float* __restrict__ x, unsigned short* __restrict__ xb,
                               int n4) {
  int idx = blockIdx.x * blockDim.x + threadIdx.x;
  if (idx >= n4) return;
  float4 v = ((const float4*)x)[idx];
  uint2 o;
  o.x = halfpair(v.x, v.y);
  o.y = halfpair(v.z, v.w);
  ((uint2*)xb)[idx] = o;
}

// ---------------- weights fp32 [k][n] -> fp16 LDS-image [n][swz(perm(k))] ----------------

__global__ void wconv_kernel(const float* __restrict__ w1, const float* __restrict__ fc1w,
                             unsigned short* __restrict__ dst) {
  int idx = blockIdx.x * blockDim.x + threadIdx.x;  // 5*16384
  if (idx >= 5 * FEAT * FEAT) return;
  int m = idx >> 14;
  int r = idx & (FEAT * FEAT - 1);
  int k = r >> 7, n = r & 127;
  float v = (m < 4) ? w1[idx] : fc1w[r];
  int p = kperm(k);
  int slot = p >> 3, e = p & 7;
  dst[m * FEAT * FEAT + n * FEAT + ((slot ^ (n & 7)) << 3) + e] = halfr(v);
}

// ---------------- aggregation: 4 nodes/wave (16 lanes x uint4 = 256B row) ----------------

__global__ void agg_kernel(const unsigned short* __restrict__ x, const int* __restrict__ rowptr,
                           const int* __restrict__ col, unsigned short* __restrict__ agg, int N) {
  int gid = blockIdx.x * blockDim.x + threadIdx.x;
  int wid = gid >> 6;
  int lane = threadIdx.x & 63;
  int node = wid * 4 + (lane >> 4);
  if (node >= N) return;
  int ln = lane & 15;
  const uint4* xr = (const uint4*)x;  // 16 uint4 per row
  uint4 s = xr[(size_t)node * 16 + ln];
  float2 t0 = halfup(s.x), t1 = halfup(s.y), t2 = halfup(s.z), t3 = halfup(s.w);
  float a0 = t0.x, a1 = t0.y, a2 = t1.x, a3 = t1.y;
  float a4 = t2.x, a5 = t2.y, a6 = t3.x, a7 = t3.y;
  float b0 = 0.f, b1 = 0.f, b2 = 0.f, b3 = 0.f;
  float b4 = 0.f, b5 = 0.f, b6 = 0.f, b7 = 0.f;
  int e0 = rowptr[node], e1 = rowptr[node + 1];
  int e = e0;
  for (; e + 1 < e1; e += 2) {
    int c0 = col[e], c1 = col[e + 1];
    uint4 v = xr[(size_t)c0 * 16 + ln];
    uint4 u = xr[(size_t)c1 * 16 + ln];
    float2 v0 = halfup(v.x), v1 = halfup(v.y), v2 = halfup(v.z), v3 = halfup(v.w);
    float2 u0 = halfup(u.x), u1 = halfup(u.y), u2 = halfup(u.z), u3 = halfup(u.w);
    a0 += v0.x; a1 += v0.y; a2 += v1.x; a3 += v1.y;
    a4 += v2.x; a5 += v2.y; a6 += v3.x; a7 += v3.y;
    b0 += u0.x; b1 += u0.y; b2 += u1.x; b3 += u1.y;
    b4 += u2.x; b5 += u2.y; b6 += u3.x; b7 += u3.y;
  }
  if (e < e1) {
    uint4 v = xr[(size_t)col[e] * 16 + ln];
    float2 v0 = halfup(v.x), v1 = halfup(v.y), v2 = halfup(v.z), v3 = halfup(v.w);
    a0 += v0.x; a1 += v0.y; a2 += v1.x; a3 += v1.y;
    a4 += v2.x; a5 += v2.y; a6 += v3.x; a7 += v3.y;
  }
  a0 += b0; a1 += b1; a2 += b2; a3 += b3;
  a4 += b4; a5 += b5; a6 += b6; a7 += b7;
  uint4 o;
  o.x = halfpair(a0, a1);
  o.y = halfpair(a2, a3);
  o.z = halfpair(a4, a5);
  o.w = halfpair(a6, a7);
  ((uint4*)agg)[(size_t)node * 16 + ln] = o;
}

// ---------------- fp16 MFMA GEMM: C = relu(A@W + b), fp32 acc ----------------

__global__ __launch_bounds__(256) void gemm_kernel(
    const unsigned short* __restrict__ A, const unsigned short* __restrict__ Wimg,
    const float* __restrict__ bias, unsigned short* __restrict__ C,
    float* __restrict__ pS, float* __restrict__ pQ, int N, int doStats) {
  __shared__ unsigned short Al[FEAT * FEAT];  // 32KB
  __shared__ unsigned short Wl[FEAT * FEAT];  // 32KB
  __shared__ float ls[FEAT], lq[FEAT];

  int tx = threadIdx.x;
  int row0 = blockIdx.x * FEAT;
  if (tx < FEAT) { ls[tx] = 0.f; lq[tx] = 0.f; }

#pragma unroll
  for (int i = 0; i < 8; i++) {
    int idx = tx + i * 256;
    ((uint4*)Wl)[idx] = ((const uint4*)Wimg)[idx];
  }
#pragma unroll
  for (int i = 0; i < 16; i++) {
    int idx = tx + i * 256;  // 4096 uint2 chunks = 128 rows x 32
    int r = idx >> 5;
    int c = idx & 31;
    uint2 v = make_uint2(0u, 0u);
    if (row0 + r < N) v = ((const uint2*)(A + (size_t)(row0 + r) * FEAT))[c];
    int k0 = c << 2;
    int p0 = ((k0 >> 5) << 5) + (((k0 >> 2) & 3) << 3) + (((k0 >> 4) & 1) << 2);
    int slot = p0 >> 3, half4 = (p0 >> 2) & 1;
    *(uint2*)&Al[r * FEAT + ((slot ^ (r & 7)) << 3) + (half4 << 2)] = v;
  }
  __syncthreads();

  int w = tx >> 6;
  int l = tx & 63;
  int llo = l & 15, lhi = l >> 4;
  int wr = (w >> 1) * 64, wc = (w & 1) * 64;

  f32x4 acc[4][4];
#pragma unroll
  for (int mi = 0; mi < 4; mi++)
#pragma unroll
    for (int nj = 0; nj < 4; nj++) acc[mi][nj] = (f32x4)(0.f);

#pragma unroll
  for (int s = 0; s < 4; s++) {
    f16x8 af[4], wf[4];
#pragma unroll
    for (int mi = 0; mi < 4; mi++) {
      int row = wr + mi * 16 + llo;
      int base = row * FEAT + ((((s << 2) + lhi) ^ (row & 7)) << 3);
      af[mi] = *(const f16x8*)&Al[base];
    }
#pragma unroll
    for (int nj = 0; nj < 4; nj++) {
      int n = wc + nj * 16 + llo;
      int base = n * FEAT + ((((s << 2) + lhi) ^ (n & 7)) << 3);
      wf[nj] = *(const f16x8*)&Wl[base];
    }
#pragma unroll
    for (int mi = 0; mi < 4; mi++)
#pragma unroll
      for (int nj = 0; nj < 4; nj++)
        acc[mi][nj] = __builtin_amdgcn_mfma_f32_16x16x32_f16(wf[nj], af[mi], acc[mi][nj], 0, 0, 0);
  }

#pragma unroll
  for (int nj = 0; nj < 4; nj++) {
    int colb = wc + nj * 16 + lhi * 4;
    float4 bb = *(const float4*)&bias[colb];
    float ps[4] = {0.f, 0.f, 0.f, 0.f}, pq[4] = {0.f, 0.f, 0.f, 0.f};
#pragma unroll
    for (int mi = 0; mi < 4; mi++) {
      int row = row0 + wr + mi * 16 + llo;
      f32x4 v = acc[mi][nj];
      float v0 = fmaxf(v[0] + bb.x, 0.f);
      float v1 = fmaxf(v[1] + bb.y, 0.f);
      float v2 = fmaxf(v[2] + bb.z, 0.f);
      float v3 = fmaxf(v[3] + bb.w, 0.f);
      if (row < N) {
        *(uint2*)&C[(size_t)row * FEAT + colb] = make_uint2(halfpair(v0, v1), halfpair(v2, v3));
        ps[0] += v0; ps[1] += v1; ps[2] += v2; ps[3] += v3;
        pq[0] += v0 * v0; pq[1] += v1 * v1; pq[2] += v2 * v2; pq[3] += v3 * v3;
      }
    }
    if (doStats) {
#pragma unroll
      for (int r = 0; r < 4; r++) {
        float s2 = ps[r], q2 = pq[r];
#pragma unroll
        for (int off = 1; off < 16; off <<= 1) {
          s2 += __shfl_xor(s2, off);
          q2 += __shfl_xor(q2, off);
        }
        if (llo == 0) {
          atomicAdd(&ls[colb + r], s2);
          atomicAdd(&lq[colb + r], q2);
        }
      }
    }
  }
  if (doStats) {
    __syncthreads();
    if (tx < FEAT) {
      pS[(size_t)blockIdx.x * FEAT + tx] = ls[tx];
      pQ[(size_t)blockIdx.x * FEAT + tx] = lq[tx];
    }
  }
}

// ---------------- BN stats: one block per column, parallel partial reduce ----------------

__global__ __launch_bounds__(64) void stats_kernel(
    const float* __restrict__ pS, const float* __restrict__ pQ, int nblk,
    const float* __restrict__ gamma, const float* __restrict__ beta,
    float* __restrict__ scf, float* __restrict__ shf, int N) {
  int c = blockIdx.x;
  int ln = threadIdx.x;
  float s = 0.f, q = 0.f;
  for (int b = ln; b < nblk; b += 64) {
    s += pS[(size_t)b * FEAT + c];
    q += pQ[(size_t)b * FEAT + c];
  }
#pragma unroll
  for (int off = 32; off; off >>= 1) {
    s += __shfl_xor(s, off);
    q += __shfl_xor(q, off);
  }
  if (ln == 0) {
    float invN = 1.0f / (float)N;
    float mean = s * invN;
    float var = q * invN - mean * mean;
    float rstd = rsqrtf(var + 1e-5f);
    float scale = gamma[c] * rstd;
    scf[c] = scale;
    shf[c] = beta[c] - mean * scale;
  }
}

// ---------------- fold: one block per out-col, thread per k ----------------

__global__ __launch_bounds__(128) void fold2_kernel(
    const float* __restrict__ scf, const float* __restrict__ shf,
    const float* __restrict__ w2, const float* __restrict__ b2,
    unsigned short* __restrict__ w2f, float* __restrict__ b2f) {
  __shared__ float red[FEAT];
  int c = blockIdx.x;
  int k = threadIdx.x;
  float wv = w2[k * FEAT + c];
  int p = kperm(k);
  int slot = p >> 3, e = p & 7;
  w2f[c * FEAT + ((slot ^ (c & 7)) << 3) + e] = halfr(scf[k] * wv);
  red[k] = shf[k] * wv;
  __syncthreads();
#pragma unroll
  for (int off = 64; off > 0; off >>= 1) {
    if (k < off) red[k] += red[k + off];
    __syncthreads();
  }
  if (k == 0) b2f[c] = b2[c] + red[0];
}

// ---------------- final fc2 (fp16 in) ----------------

__global__ void fc2_kernel(const unsigned short* __restrict__ h, const float* __restrict__ w,
                           const float* __restrict__ b, float* __restrict__ out, int N) {
  int gid = blockIdx.x * blockDim.x + threadIdx.x;
  int node = gid >> 6;
  if (node >= N) return;
  int lane = threadIdx.x & 63;
  float2 hv = halfup(((const unsigned int*)h)[(size_t)node * 64 + lane]);
  float2 wv = ((const float2*)w)[lane];
  float s = hv.x * wv.x + hv.y * wv.y;
#pragma unroll
  for (int off = 32; off; off >>= 1) s += __shfl_xor(s, off);
  if (lane == 0) out[node] = s + b[0];
}

// ---------------- launch ----------------

extern "C" void kernel_launch(void* const* d_in, const int* in_sizes, int n_in,
                              void* d_out, int out_size, void* d_ws, size_t ws_size,
                              hipStream_t stream) {
  const float* x     = (const float*)d_in[0];
  const int*   ei    = (const int*)d_in[1];
  const float* w1    = (const float*)d_in[2];
  const float* b1    = (const float*)d_in[3];
  const float* gamma = (const float*)d_in[4];
  const float* beta  = (const float*)d_in[5];
  const float* w2    = (const float*)d_in[6];
  const float* b2    = (const float*)d_in[7];
  const float* fc1w  = (const float*)d_in[8];
  const float* fc1b  = (const float*)d_in[9];
  const float* fc2w  = (const float*)d_in[10];
  const float* fc2b  = (const float*)d_in[11];
  float* out = (float*)d_out;

  int N = in_sizes[0] / FEAT;  // 50000
  int E = in_sizes[1] / 2;     // 600000
  const int* srcI = ei;
  const int* dstI = ei + E;

  int gemmBlocks = (N + FEAT - 1) / FEAT;

  size_t Nf = (size_t)N * FEAT;
  unsigned short* H = (unsigned short*)d_ws;       // fp16 activations (gather source)
  unsigned short* G = H + Nf;                      // fp16 work buffer
  unsigned short* wimg = G + Nf;                   // 5 fp16 weight images (w1 x4, fc1)
  unsigned short* w2f = wimg + 5 * FEAT * FEAT;    // folded gemm2 weight image
  float* b2f = (float*)(w2f + FEAT * FEAT);
  float* scf = b2f + FEAT;
  float* shf = scf + FEAT;
  float* pS = shf + FEAT;
  float* pQ = pS + (size_t)gemmBlocks * FEAT;
  int* deg = (int*)(pQ + (size_t)gemmBlocks * FEAT);
  int* rowptr = deg + (N + 1);
  int* cursor = rowptr + (N + 1);
  int* col = cursor + (N + 1);

  // CSR build
  hipMemsetAsync(deg, 0, (N + 1) * sizeof(int), stream);
  count_kernel<<<(E + 255) / 256, 256, 0, stream>>>(dstI, deg, E);
  scan_kernel<<<1, 1024, 0, stream>>>(deg, rowptr, cursor, N + 1);
  fill_kernel<<<(E + 255) / 256, 256, 0, stream>>>(srcI, dstI, cursor, col, E);

  // fp16 conversions
  int n4 = (int)(Nf / 4);
  convert_kernel<<<(n4 + 255) / 256, 256, 0, stream>>>(x, H, n4);
  wconv_kernel<<<(5 * FEAT * FEAT + 255) / 256, 256, 0, stream>>>(w1, fc1w, wimg);

  int aggBlocks = (int)((((size_t)(N + 3) / 4) * 64 + 255) / 256);
  int fc2Blocks = (int)(((size_t)N * 64 + 255) / 256);

  for (int l = 0; l < 4; l++) {
    agg_kernel<<<aggBlocks, 256, 0, stream>>>(H, rowptr, col, G, N);
    gemm_kernel<<<gemmBlocks, 256, 0, stream>>>(G, wimg + (size_t)l * FEAT * FEAT,
                                                b1 + (size_t)l * FEAT, G, pS, pQ, N, 1);
    stats_kernel<<<FEAT, 64, 0, stream>>>(pS, pQ, gemmBlocks, gamma + (size_t)l * FEAT,
                                          beta + (size_t)l * FEAT, scf, shf, N);
    fold2_kernel<<<FEAT, FEAT, 0, stream>>>(scf, shf, w2 + (size_t)l * FEAT * FEAT,
                                            b2 + (size_t)l * FEAT, w2f, b2f);
    gemm_kernel<<<gemmBlocks, 256, 0, stream>>>(G, w2f, b2f, H, nullptr, nullptr, N, 0);
  }

  // fc1: H -> G (relu), fc2: G -> out
  gemm_kernel<<<gemmBlocks, 256, 0, stream>>>(H, wimg + (size_t)4 * FEAT * FEAT, fc1b, G,
                                              nullptr, nullptr, N, 0);
  fc2_kernel<<<fc2Blocks, 256, 0, stream>>>(G, fc2w, fc2b, out, N);
}

// Round 8
// 425.182 us; speedup vs baseline: 2.5058x; 1.1178x over previous
//
#include <hip/hip_runtime.h>

constexpr int FEAT = 128;

typedef __attribute__((ext_vector_type(8))) _Float16 f16x8;
typedef __attribute__((ext_vector_type(4))) float f32x4;

// ---------- fp16 helpers ----------
__device__ inline unsigned int halfpair(float a, float b) {
  unsigned short ua = __builtin_bit_cast(unsigned short, (_Float16)a);
  unsigned short ub = __builtin_bit_cast(unsigned short, (_Float16)b);
  return (unsigned int)ua | ((unsigned int)ub << 16);
}
__device__ inline unsigned short halfr(float a) {
  return __builtin_bit_cast(unsigned short, (_Float16)a);
}
__device__ inline float2 halfup(unsigned int u) {
  _Float16 lo = __builtin_bit_cast(_Float16, (unsigned short)(u & 0xffffu));
  _Float16 hi = __builtin_bit_cast(_Float16, (unsigned short)(u >> 16));
  return make_float2((float)lo, (float)hi);
}

// K-permutation for mfma 16x16x32 fragments (layout verified by passing rounds)
__device__ __host__ inline int kperm(int k) {
  return ((k >> 5) << 5) + (((k >> 2) & 3) << 3) + (((k >> 4) & 1) << 2) + (k & 3);
}

// ---------------- CSR build ----------------

__global__ void count_kernel(const int* __restrict__ dst, int* __restrict__ deg, int E) {
  int e = blockIdx.x * blockDim.x + threadIdx.x;
  if (e < E) atomicAdd(&deg[dst[e]], 1);
}

// 3-phase parallel exclusive scan over n elements (n <= 65536: block sums fit one wave)
// phase 1: per-block (1024 elems) sums
__global__ __launch_bounds__(256) void scan1_kernel(const int* __restrict__ in,
                                                    int* __restrict__ bsum, int n) {
  int base = blockIdx.x * 1024 + threadIdx.x * 4;
  int s = 0;
  if (base + 3 < n) {
    int4 v = *(const int4*)(in + base);
    s = v.x + v.y + v.z + v.w;
  } else {
#pragma unroll
    for (int j = 0; j < 4; j++)
      if (base + j < n) s += in[base + j];
  }
#pragma unroll
  for (int off = 1; off < 64; off <<= 1) s += __shfl_xor(s, off);
  __shared__ int ws[4];
  int lane = threadIdx.x & 63, wid = threadIdx.x >> 6;
  if (lane == 0) ws[wid] = s;
  __syncthreads();
  if (threadIdx.x == 0) bsum[blockIdx.x] = ws[0] + ws[1] + ws[2] + ws[3];
}

// phase 2: single-wave exclusive scan of block sums (nb <= 64)
__global__ __launch_bounds__(64) void scan2_kernel(int* __restrict__ bsum, int nb) {
  int t = threadIdx.x;
  int v = (t < nb) ? bsum[t] : 0;
  int s = v;
#pragma unroll
  for (int off = 1; off < 64; off <<= 1) {
    int u = __shfl_up(s, off);
    if (t >= off) s += u;
  }
  if (t < nb) bsum[t] = s - v;
}

// phase 3: per-block exclusive scan + block offset, dual output (rowptr + cursor)
__global__ __launch_bounds__(256) void scan3_kernel(const int* __restrict__ in,
                                                    const int* __restrict__ boff,
                                                    int* __restrict__ out,
                                                    int* __restrict__ out2, int n) {
  int t = threadIdx.x;
  int base = blockIdx.x * 1024 + t * 4;
  int v0 = 0, v1 = 0, v2 = 0, v3 = 0;
  if (base + 3 < n) {
    int4 v = *(const int4*)(in + base);
    v0 = v.x; v1 = v.y; v2 = v.z; v3 = v.w;
  } else {
    if (base + 0 < n) v0 = in[base + 0];
    if (base + 1 < n) v1 = in[base + 1];
    if (base + 2 < n) v2 = in[base + 2];
  }
  int ts = v0 + v1 + v2 + v3;
  int s = ts;
  int lane = t & 63, wid = t >> 6;
#pragma unroll
  for (int off = 1; off < 64; off <<= 1) {
    int u = __shfl_up(s, off);
    if (lane >= off) s += u;
  }
  __shared__ int ws[4];
  if (lane == 63) ws[wid] = s;
  __syncthreads();
  int cross = 0;
#pragma unroll
  for (int i = 0; i < 4; i++)
    if (i < wid) cross += ws[i];
  int excl = boff[blockIdx.x] + cross + (s - ts);
  int o0 = excl, o1 = o0 + v0, o2 = o1 + v1, o3 = o2 + v2;
  if (base + 3 < n) {
    *(int4*)(out + base) = make_int4(o0, o1, o2, o3);
    *(int4*)(out2 + base) = make_int4(o0, o1, o2, o3);
  } else {
    if (base + 0 < n) { out[base + 0] = o0; out2[base + 0] = o0; }
    if (base + 1 < n) { out[base + 1] = o1; out2[base + 1] = o1; }
    if (base + 2 < n) { out[base + 2] = o2; out2[base + 2] = o2; }
  }
}

__global__ void fill_kernel(const int* __restrict__ src, const int* __restrict__ dst,
                            int* __restrict__ cursor, int* __restrict__ col, int E) {
  int e = blockIdx.x * blockDim.x + threadIdx.x;
  if (e < E) {
    int p = atomicAdd(&cursor[dst[e]], 1);
    col[p] = src[e];
  }
}

// ---------------- x fp32 -> fp16 ----------------

__global__ void convert_kernel(const float* __restrict__ x, unsigned short* __restrict__ xb,
                               int n4) {
  int idx = blockIdx.x * blockDim.x + threadIdx.x;
  if (idx >= n4) return;
  float4 v = ((const float4*)x)[idx];
  uint2 o;
  o.x = halfpair(v.x, v.y);
  o.y = halfpair(v.z, v.w);
  ((uint2*)xb)[idx] = o;
}

// ---------------- weights fp32 [k][n] -> fp16 LDS-image [n][swz(perm(k))] ----------------

__global__ void wconv_kernel(const float* __restrict__ w1, const float* __restrict__ fc1w,
                             unsigned short* __restrict__ dst) {
  int idx = blockIdx.x * blockDim.x + threadIdx.x;  // 5*16384
  if (idx >= 5 * FEAT * FEAT) return;
  int m = idx >> 14;
  int r = idx & (FEAT * FEAT - 1);
  int k = r >> 7, n = r & 127;
  float v = (m < 4) ? w1[idx] : fc1w[r];
  int p = kperm(k);
  int slot = p >> 3, e = p & 7;
  dst[m * FEAT * FEAT + n * FEAT + ((slot ^ (n & 7)) << 3) + e] = halfr(v);
}

// ---------------- aggregation: 4 nodes/wave (16 lanes x uint4), edges unroll-4 ----------------

__global__ void agg_kernel(const unsigned short* __restrict__ x, const int* __restrict__ rowptr,
                           const int* __restrict__ col, unsigned short* __restrict__ agg, int N) {
  int gid = blockIdx.x * blockDim.x + threadIdx.x;
  int wid = gid >> 6;
  int lane = threadIdx.x & 63;
  int node = wid * 4 + (lane >> 4);
  if (node >= N) return;
  int ln = lane & 15;
  const uint4* xr = (const uint4*)x;  // 16 uint4 per row
  uint4 s = xr[(size_t)node * 16 + ln];
  float2 t0 = halfup(s.x), t1 = halfup(s.y), t2 = halfup(s.z), t3 = halfup(s.w);
  float a0 = t0.x, a1 = t0.y, a2 = t1.x, a3 = t1.y;
  float a4 = t2.x, a5 = t2.y, a6 = t3.x, a7 = t3.y;
  float b0 = 0.f, b1 = 0.f, b2 = 0.f, b3 = 0.f;
  float b4 = 0.f, b5 = 0.f, b6 = 0.f, b7 = 0.f;
  int e0 = rowptr[node], e1 = rowptr[node + 1];
  int e = e0;
  for (; e + 3 < e1; e += 4) {
    int c0 = col[e], c1 = col[e + 1], c2 = col[e + 2], c3 = col[e + 3];
    uint4 v = xr[(size_t)c0 * 16 + ln];
    uint4 u = xr[(size_t)c1 * 16 + ln];
    uint4 w = xr[(size_t)c2 * 16 + ln];
    uint4 z = xr[(size_t)c3 * 16 + ln];
    float2 f;
    f = halfup(v.x); a0 += f.x; a1 += f.y;
    f = halfup(v.y); a2 += f.x; a3 += f.y;
    f = halfup(v.z); a4 += f.x; a5 += f.y;
    f = halfup(v.w); a6 += f.x; a7 += f.y;
    f = halfup(u.x); b0 += f.x; b1 += f.y;
    f = halfup(u.y); b2 += f.x; b3 += f.y;
    f = halfup(u.z); b4 += f.x; b5 += f.y;
    f = halfup(u.w); b6 += f.x; b7 += f.y;
    f = halfup(w.x); a0 += f.x; a1 += f.y;
    f = halfup(w.y); a2 += f.x; a3 += f.y;
    f = halfup(w.z); a4 += f.x; a5 += f.y;
    f = halfup(w.w); a6 += f.x; a7 += f.y;
    f = halfup(z.x); b0 += f.x; b1 += f.y;
    f = halfup(z.y); b2 += f.x; b3 += f.y;
    f = halfup(z.z); b4 += f.x; b5 += f.y;
    f = halfup(z.w); b6 += f.x; b7 += f.y;
  }
  for (; e < e1; e++) {
    uint4 v = xr[(size_t)col[e] * 16 + ln];
    float2 f;
    f = halfup(v.x); a0 += f.x; a1 += f.y;
    f = halfup(v.y); a2 += f.x; a3 += f.y;
    f = halfup(v.z); a4 += f.x; a5 += f.y;
    f = halfup(v.w); a6 += f.x; a7 += f.y;
  }
  a0 += b0; a1 += b1; a2 += b2; a3 += b3;
  a4 += b4; a5 += b5; a6 += b6; a7 += b7;
  uint4 o;
  o.x = halfpair(a0, a1);
  o.y = halfpair(a2, a3);
  o.z = halfpair(a4, a5);
  o.w = halfpair(a6, a7);
  ((uint4*)agg)[(size_t)node * 16 + ln] = o;
}

// ---------------- fp16 MFMA GEMM: C = relu(A@W + b), fp32 acc ----------------

__global__ __launch_bounds__(256) void gemm_kernel(
    const unsigned short* __restrict__ A, const unsigned short* __restrict__ Wimg,
    const float* __restrict__ bias, unsigned short* __restrict__ C,
    float* __restrict__ pS, float* __restrict__ pQ, int N, int doStats) {
  __shared__ unsigned short Al[FEAT * FEAT];  // 32KB
  __shared__ unsigned short Wl[FEAT * FEAT];  // 32KB
  __shared__ float ls[FEAT], lq[FEAT];

  int tx = threadIdx.x;
  int row0 = blockIdx.x * FEAT;
  if (tx < FEAT) { ls[tx] = 0.f; lq[tx] = 0.f; }

#pragma unroll
  for (int i = 0; i < 8; i++) {
    int idx = tx + i * 256;
    ((uint4*)Wl)[idx] = ((const uint4*)Wimg)[idx];
  }
#pragma unroll
  for (int i = 0; i < 16; i++) {
    int idx = tx + i * 256;  // 4096 uint2 chunks = 128 rows x 32
    int r = idx >> 5;
    int c = idx & 31;
    uint2 v = make_uint2(0u, 0u);
    if (row0 + r < N) v = ((const uint2*)(A + (size_t)(row0 + r) * FEAT))[c];
    int k0 = c << 2;
    int p0 = ((k0 >> 5) << 5) + (((k0 >> 2) & 3) << 3) + (((k0 >> 4) & 1) << 2);
    int slot = p0 >> 3, half4 = (p0 >> 2) & 1;
    *(uint2*)&Al[r * FEAT + ((slot ^ (r & 7)) << 3) + (half4 << 2)] = v;
  }
  __syncthreads();

  int w = tx >> 6;
  int l = tx & 63;
  int llo = l & 15, lhi = l >> 4;
  int wr = (w >> 1) * 64, wc = (w & 1) * 64;

  f32x4 acc[4][4];
#pragma unroll
  for (int mi = 0; mi < 4; mi++)
#pragma unroll
    for (int nj = 0; nj < 4; nj++) acc[mi][nj] = (f32x4)(0.f);

#pragma unroll
  for (int s = 0; s < 4; s++) {
    f16x8 af[4], wf[4];
#pragma unroll
    for (int mi = 0; mi < 4; mi++) {
      int row = wr + mi * 16 + llo;
      int base = row * FEAT + ((((s << 2) + lhi) ^ (row & 7)) << 3);
      af[mi] = *(const f16x8*)&Al[base];
    }
#pragma unroll
    for (int nj = 0; nj < 4; nj++) {
      int n = wc + nj * 16 + llo;
      int base = n * FEAT + ((((s << 2) + lhi) ^ (n & 7)) << 3);
      wf[nj] = *(const f16x8*)&Wl[base];
    }
#pragma unroll
    for (int mi = 0; mi < 4; mi++)
#pragma unroll
      for (int nj = 0; nj < 4; nj++)
        acc[mi][nj] = __builtin_amdgcn_mfma_f32_16x16x32_f16(wf[nj], af[mi], acc[mi][nj], 0, 0, 0);
  }

#pragma unroll
  for (int nj = 0; nj < 4; nj++) {
    int colb = wc + nj * 16 + lhi * 4;
    float4 bb = *(const float4*)&bias[colb];
    float ps[4] = {0.f, 0.f, 0.f, 0.f}, pq[4] = {0.f, 0.f, 0.f, 0.f};
#pragma unroll
    for (int mi = 0; mi < 4; mi++) {
      int row = row0 + wr + mi * 16 + llo;
      f32x4 v = acc[mi][nj];
      float v0 = fmaxf(v[0] + bb.x, 0.f);
      float v1 = fmaxf(v[1] + bb.y, 0.f);
      float v2 = fmaxf(v[2] + bb.z, 0.f);
      float v3 = fmaxf(v[3] + bb.w, 0.f);
      if (row < N) {
        *(uint2*)&C[(size_t)row * FEAT + colb] = make_uint2(halfpair(v0, v1), halfpair(v2, v3));
        ps[0] += v0; ps[1] += v1; ps[2] += v2; ps[3] += v3;
        pq[0] += v0 * v0; pq[1] += v1 * v1; pq[2] += v2 * v2; pq[3] += v3 * v3;
      }
    }
    if (doStats) {
#pragma unroll
      for (int r = 0; r < 4; r++) {
        float s2 = ps[r], q2 = pq[r];
#pragma unroll
        for (int off = 1; off < 16; off <<= 1) {
          s2 += __shfl_xor(s2, off);
          q2 += __shfl_xor(q2, off);
        }
        if (llo == 0) {
          atomicAdd(&ls[colb + r], s2);
          atomicAdd(&lq[colb + r], q2);
        }
      }
    }
  }
  if (doStats) {
    __syncthreads();
    if (tx < FEAT) {
      pS[(size_t)blockIdx.x * FEAT + tx] = ls[tx];
      pQ[(size_t)blockIdx.x * FEAT + tx] = lq[tx];
    }
  }
}

// ---------------- BN stats: one block per column, parallel partial reduce ----------------

__global__ __launch_bounds__(64) void stats_kernel(
    const float* __restrict__ pS, const float* __restrict__ pQ, int nblk,
    const float* __restrict__ gamma, const float* __restrict__ beta,
    float* __restrict__ scf, float* __restrict__ shf, int N) {
  int c = blockIdx.x;
  int ln = threadIdx.x;
  float s = 0.f, q = 0.f;
  for (int b = ln; b < nblk; b += 64) {
    s += pS[(size_t)b * FEAT + c];
    q += pQ[(size_t)b * FEAT + c];
  }
#pragma unroll
  for (int off = 32; off; off >>= 1) {
    s += __shfl_xor(s, off);
    q += __shfl_xor(q, off);
  }
  if (ln == 0) {
    float invN = 1.0f / (float)N;
    float mean = s * invN;
    float var = q * invN - mean * mean;
    float rstd = rsqrtf(var + 1e-5f);
    float scale = gamma[c] * rstd;
    scf[c] = scale;
    shf[c] = beta[c] - mean * scale;
  }
}

// ---------------- fold: one block per out-col, thread per k ----------------

__global__ __launch_bounds__(128) void fold2_kernel(
    const float* __restrict__ scf, const float* __restrict__ shf,
    const float* __restrict__ w2, const float* __restrict__ b2,
    unsigned short* __restrict__ w2f, float* __restrict__ b2f) {
  __shared__ float red[FEAT];
  int c = blockIdx.x;
  int k = threadIdx.x;
  float wv = w2[k * FEAT + c];
  int p = kperm(k);
  int slot = p >> 3, e = p & 7;
  w2f[c * FEAT + ((slot ^ (c & 7)) << 3) + e] = halfr(scf[k] * wv);
  red[k] = shf[k] * wv;
  __syncthreads();
#pragma unroll
  for (int off = 64; off > 0; off >>= 1) {
    if (k < off) red[k] += red[k + off];
    __syncthreads();
  }
  if (k == 0) b2f[c] = b2[c] + red[0];
}

// ---------------- final fc2 (fp16 in) ----------------

__global__ void fc2_kernel(const unsigned short* __restrict__ h, const float* __restrict__ w,
                           const float* __restrict__ b, float* __restrict__ out, int N) {
  int gid = blockIdx.x * blockDim.x + threadIdx.x;
  int node = gid >> 6;
  if (node >= N) return;
  int lane = threadIdx.x & 63;
  float2 hv = halfup(((const unsigned int*)h)[(size_t)node * 64 + lane]);
  float2 wv = ((const float2*)w)[lane];
  float s = hv.x * wv.x + hv.y * wv.y;
#pragma unroll
  for (int off = 32; off; off >>= 1) s += __shfl_xor(s, off);
  if (lane == 0) out[node] = s + b[0];
}

// ---------------- launch ----------------

extern "C" void kernel_launch(void* const* d_in, const int* in_sizes, int n_in,
                              void* d_out, int out_size, void* d_ws, size_t ws_size,
                              hipStream_t stream) {
  const float* x     = (const float*)d_in[0];
  const int*   ei    = (const int*)d_in[1];
  const float* w1    = (const float*)d_in[2];
  const float* b1    = (const float*)d_in[3];
  const float* gamma = (const float*)d_in[4];
  const float* beta  = (const float*)d_in[5];
  const float* w2    = (const float*)d_in[6];
  const float* b2    = (const float*)d_in[7];
  const float* fc1w  = (const float*)d_in[8];
  const float* fc1b  = (const float*)d_in[9];
  const float* fc2w  = (const float*)d_in[10];
  const float* fc2b  = (const float*)d_in[11];
  float* out = (float*)d_out;

  int N = in_sizes[0] / FEAT;  // 50000
  int E = in_sizes[1] / 2;     // 600000
  const int* srcI = ei;
  const int* dstI = ei + E;

  int gemmBlocks = (N + FEAT - 1) / FEAT;
  int n = N + 1;
  int nb = (n + 1023) / 1024;  // scan blocks (<= 64)

  size_t Nf = (size_t)N * FEAT;
  unsigned short* H = (unsigned short*)d_ws;       // fp16 activations (gather source)
  unsigned short* G = H + Nf;                      // fp16 work buffer
  unsigned short* wimg = G + Nf;                   // 5 fp16 weight images (w1 x4, fc1)
  unsigned short* w2f = wimg + 5 * FEAT * FEAT;    // folded gemm2 weight image
  float* b2f = (float*)(w2f + FEAT * FEAT);
  float* scf = b2f + FEAT;
  float* shf = scf + FEAT;
  float* pS = shf + FEAT;
  float* pQ = pS + (size_t)gemmBlocks * FEAT;
  int* deg = (int*)(pQ + (size_t)gemmBlocks * FEAT);
  int* rowptr = deg + ((n + 3) & ~3);
  int* cursor = rowptr + ((n + 3) & ~3);
  int* bsum = cursor + ((n + 3) & ~3);
  int* col = bsum + 64;

  // CSR build
  hipMemsetAsync(deg, 0, n * sizeof(int), stream);
  count_kernel<<<(E + 255) / 256, 256, 0, stream>>>(dstI, deg, E);
  scan1_kernel<<<nb, 256, 0, stream>>>(deg, bsum, n);
  scan2_kernel<<<1, 64, 0, stream>>>(bsum, nb);
  scan3_kernel<<<nb, 256, 0, stream>>>(deg, bsum, rowptr, cursor, n);
  fill_kernel<<<(E + 255) / 256, 256, 0, stream>>>(srcI, dstI, cursor, col, E);

  // fp16 conversions
  int n4 = (int)(Nf / 4);
  convert_kernel<<<(n4 + 255) / 256, 256, 0, stream>>>(x, H, n4);
  wconv_kernel<<<(5 * FEAT * FEAT + 255) / 256, 256, 0, stream>>>(w1, fc1w, wimg);

  int aggBlocks = (int)((((size_t)(N + 3) / 4) * 64 + 255) / 256);
  int fc2Blocks = (int)(((size_t)N * 64 + 255) / 256);

  for (int l = 0; l < 4; l++) {
    agg_kernel<<<aggBlocks, 256, 0, stream>>>(H, rowptr, col, G, N);
    gemm_kernel<<<gemmBlocks, 256, 0, stream>>>(G, wimg + (size_t)l * FEAT * FEAT,
                                                b1 + (size_t)l * FEAT, G, pS, pQ, N, 1);
    stats_kernel<<<FEAT, 64, 0, stream>>>(pS, pQ, gemmBlocks, gamma + (size_t)l * FEAT,
                                          beta + (size_t)l * FEAT, scf, shf, N);
    fold2_kernel<<<FEAT, FEAT, 0, stream>>>(scf, shf, w2 + (size_t)l * FEAT * FEAT,
                                            b2 + (size_t)l * FEAT, w2f, b2f);
    gemm_kernel<<<gemmBlocks, 256, 0, stream>>>(G, w2f, b2f, H, nullptr, nullptr, N, 0);
  }

  // fc1: H -> G (relu), fc2: G -> out
  gemm_kernel<<<gemmBlocks, 256, 0, stream>>>(H, wimg + (size_t)4 * FEAT * FEAT, fc1b, G,
                                              nullptr, nullptr, N, 0);
  fc2_kernel<<<fc2Blocks, 256, 0, stream>>>(G, fc2w, fc2b, out, N);
}